// Round 3
// baseline (108473.499 us; speedup 1.0000x reference)
//
#include <hip/hip_runtime.h>

#define BB 16
#define SS 128
#define TT 128
#define EE 512
#define HH 512
#define DD 1024
#define VO 10000
#define NBLK 512

__device__ __forceinline__ float wred(float s) {
#pragma unroll
  for (int off = 32; off >= 1; off >>= 1) s += __shfl_xor(s, off, 64);
  return s;
}
__device__ __forceinline__ float sigm(float x) { return 1.f / (1.f + expf(-x)); }

// ---- two-level grid barrier: 64 leaf lines (8 blocks each) + root + gen ----
// bar layout (uints): leaf[g]=bar[g*16] g<64; root=bar[1024]; gen=bar[1040]
__device__ __forceinline__ void gbar(unsigned* bar) {
  __syncthreads();
  if (threadIdx.x == 0) {
    unsigned* leaf = bar + ((blockIdx.x >> 3) << 4);
    unsigned* root = bar + 1024;
    unsigned* gen = bar + 1040;
    unsigned g = __hip_atomic_load(gen, __ATOMIC_RELAXED, __HIP_MEMORY_SCOPE_AGENT);
    __threadfence();
    unsigned a = __hip_atomic_fetch_add(leaf, 1u, __ATOMIC_ACQ_REL, __HIP_MEMORY_SCOPE_AGENT);
    if (a == 7u) {
      __hip_atomic_store(leaf, 0u, __ATOMIC_RELAXED, __HIP_MEMORY_SCOPE_AGENT);
      unsigned r = __hip_atomic_fetch_add(root, 1u, __ATOMIC_ACQ_REL, __HIP_MEMORY_SCOPE_AGENT);
      if (r == 63u) {
        __hip_atomic_store(root, 0u, __ATOMIC_RELAXED, __HIP_MEMORY_SCOPE_AGENT);
        __hip_atomic_store(gen, g + 1u, __ATOMIC_RELEASE, __HIP_MEMORY_SCOPE_AGENT);
      } else {
        while (__hip_atomic_load(gen, __ATOMIC_ACQUIRE, __HIP_MEMORY_SCOPE_AGENT) == g)
          __builtin_amdgcn_s_sleep(2);
      }
    } else {
      while (__hip_atomic_load(gen, __ATOMIC_ACQUIRE, __HIP_MEMORY_SCOPE_AGENT) == g)
        __builtin_amdgcn_s_sleep(2);
    }
  }
  __syncthreads();
}

// ---- embedding gather (padding_idx=0 -> zeros), out layout [Sn][B][E] ----
__global__ void gather_k(const int* __restrict__ idx, const float* __restrict__ emb,
                         float* __restrict__ out, int Sn) {
  const int s = blockIdx.x, b = blockIdx.y, tid = threadIdx.x;
  const int id = idx[b * Sn + s];
  float4 v = make_float4(0.f, 0.f, 0.f, 0.f);
  if (id != 0) v = ((const float4*)(emb + (size_t)id * EE))[tid];
  ((float4*)(out + ((size_t)s * BB + b) * EE))[tid] = v;
}

// ---- G[z][n][m] = sum_k X[m,k]*W[z,n,k]  (x-part gate GEMMs, parallel) ----
template <int K>
__global__ void gemv16_k(const float* __restrict__ X, int ldx,
                         const float* __restrict__ W, int ldw,
                         float* __restrict__ G, int M, size_t wz, size_t gz) {
  const int lane = threadIdx.x & 63;
  const int n = blockIdx.x * 4 + (threadIdx.x >> 6);
  const int mg = blockIdx.y;
  const int z = blockIdx.z;
  const float* Xr = X + (size_t)mg * 16 * ldx;
  const float* Wn = W + (size_t)z * wz + (size_t)n * ldw;
  float acc[16];
#pragma unroll
  for (int j = 0; j < 16; ++j) acc[j] = 0.f;
  for (int kb = 0; kb < K / 64; ++kb) {
    const int k = kb * 64 + lane;
    const float wv = Wn[k];
#pragma unroll
    for (int j = 0; j < 16; ++j) acc[j] = fmaf(wv, Xr[(size_t)j * ldx + k], acc[j]);
  }
#pragma unroll
  for (int j = 0; j < 16; ++j) acc[j] = wred(acc[j]);
  float sel = 0.f;
#pragma unroll
  for (int j = 0; j < 16; ++j)
    if (lane == j) sel = acc[j];
  if (lane < 16) G[(size_t)z * gz + (size_t)n * M + mg * 16 + lane] = sel;
}

// ---- persistent encoder layer: 128 steps, 1 barrier/step, whh in LDS ----
__global__ __launch_bounds__(256, 2) void enc_mega_k(
    const float* __restrict__ gx, const float* __restrict__ whh,
    const float* __restrict__ bias, float* __restrict__ hbuf, float* __restrict__ cbuf,
    float* __restrict__ seq, int seq_ts, int seq_bs, unsigned* bar) {
  const int lane = threadIdx.x & 63;
  const int lw = threadIdx.x >> 6;
  const int gw = blockIdx.x * 4 + lw;  // 0..2047
  const int dir = gw >> 10;
  const int r = gw & 1023;
  const int d = r >> 1;
  const int bg = (r & 1) * 8;
  const int wi = lw >> 1;

  __shared__ float wlds[2][4][HH];
  if ((lw & 1) == 0) {
    const float* wsrc = whh + (size_t)dir * (4 * HH * HH);
    for (int g4 = 0; g4 < 4; ++g4)
      for (int k = lane; k < HH; k += 64)
        wlds[wi][g4][k] = wsrc[(size_t)(g4 * HH + d) * HH + k];
  }
  __syncthreads();

  const float bv0 = bias[dir * 4 * HH + 0 * HH + d];
  const float bv1 = bias[dir * 4 * HH + 1 * HH + d];
  const float bv2 = bias[dir * 4 * HH + 2 * HH + d];
  const float bv3 = bias[dir * 4 * HH + 3 * HH + d];
  const float* gxz = gx + (size_t)dir * ((size_t)4 * HH * 2048);
  float* cc = cbuf + dir * (BB * HH);

  for (int t = 0; t < SS; ++t) {
    const int idx = dir ? (SS - 1 - t) : t;
    const float* hp = hbuf + (t & 1) * (2 * BB * HH) + dir * (BB * HH);
    float* hn = hbuf + ((t & 1) ^ 1) * (2 * BB * HH) + dir * (BB * HH);
    float a0[8], a1[8], a2[8], a3[8];
#pragma unroll
    for (int j = 0; j < 8; ++j) { a0[j] = a1[j] = a2[j] = a3[j] = 0.f; }
#pragma unroll
    for (int kb = 0; kb < HH / 64; ++kb) {
      const int k = kb * 64 + lane;
      const float w0 = wlds[wi][0][k], w1 = wlds[wi][1][k];
      const float w2 = wlds[wi][2][k], w3 = wlds[wi][3][k];
#pragma unroll
      for (int j = 0; j < 8; ++j) {
        const float xv = hp[(bg + j) * HH + k];
        a0[j] = fmaf(w0, xv, a0[j]);
        a1[j] = fmaf(w1, xv, a1[j]);
        a2[j] = fmaf(w2, xv, a2[j]);
        a3[j] = fmaf(w3, xv, a3[j]);
      }
    }
#pragma unroll
    for (int j = 0; j < 8; ++j) {
      a0[j] = wred(a0[j]); a1[j] = wred(a1[j]);
      a2[j] = wred(a2[j]); a3[j] = wred(a3[j]);
    }
    float s0 = 0, s1 = 0, s2 = 0, s3 = 0;
#pragma unroll
    for (int j = 0; j < 8; ++j)
      if (lane == j) { s0 = a0[j]; s1 = a1[j]; s2 = a2[j]; s3 = a3[j]; }
    if (lane < 8) {
      const int b = bg + lane;
      const int m = idx * BB + b;
      s0 += bv0 + gxz[(0 * HH + d) * 2048 + m];
      s1 += bv1 + gxz[(1 * HH + d) * 2048 + m];
      s2 += bv2 + gxz[(2 * HH + d) * 2048 + m];
      s3 += bv3 + gxz[(3 * HH + d) * 2048 + m];
      const float ig = sigm(s0), fg = sigm(s1), gg = tanhf(s2), og = sigm(s3);
      const float cn = fg * cc[b * HH + d] + ig * gg;
      const float hv = og * tanhf(cn);
      cc[b * HH + d] = cn;
      hn[b * HH + d] = hv;
      seq[(size_t)idx * seq_ts + (size_t)b * seq_bs + dir * HH + d] = hv;
    }
    gbar(bar);
  }
}

// ---- decoder stage device functions ----
template <int IN1, int IN2>
__device__ __forceinline__ void stage_dec(int gw, int lane, const float* __restrict__ x1,
                                          const float* __restrict__ x2,
                                          const float* __restrict__ hprev,
                                          float* __restrict__ hnew, float* __restrict__ cbuf,
                                          const float* __restrict__ wih,
                                          const float* __restrict__ whh,
                                          const float* __restrict__ bias) {
  const int d = gw >> 1;
  const int bg = (gw & 1) * 8;
  constexpr int INW = IN1 + IN2;
  float acc[4][8];
#pragma unroll
  for (int g = 0; g < 4; ++g)
#pragma unroll
    for (int j = 0; j < 8; ++j) acc[g][j] = 0.f;

  for (int kb = 0; kb < IN1 / 64; ++kb) {
    const int k = kb * 64 + lane;
    float xv[8];
#pragma unroll
    for (int j = 0; j < 8; ++j) xv[j] = x1[(bg + j) * IN1 + k];
#pragma unroll
    for (int g = 0; g < 4; ++g) {
      const float wv = wih[(size_t)(g * DD + d) * INW + k];
#pragma unroll
      for (int j = 0; j < 8; ++j) acc[g][j] = fmaf(wv, xv[j], acc[g][j]);
    }
  }
  if constexpr (IN2 > 0) {
    for (int kb = 0; kb < IN2 / 64; ++kb) {
      const int k = kb * 64 + lane;
      float xv[8];
#pragma unroll
      for (int j = 0; j < 8; ++j) xv[j] = x2[(bg + j) * IN2 + k];
#pragma unroll
      for (int g = 0; g < 4; ++g) {
        const float wv = wih[(size_t)(g * DD + d) * INW + IN1 + k];
#pragma unroll
        for (int j = 0; j < 8; ++j) acc[g][j] = fmaf(wv, xv[j], acc[g][j]);
      }
    }
  }
  for (int kb = 0; kb < DD / 64; ++kb) {
    const int k = kb * 64 + lane;
    float xv[8];
#pragma unroll
    for (int j = 0; j < 8; ++j) xv[j] = hprev[(bg + j) * DD + k];
#pragma unroll
    for (int g = 0; g < 4; ++g) {
      const float wv = whh[(size_t)(g * DD + d) * DD + k];
#pragma unroll
      for (int j = 0; j < 8; ++j) acc[g][j] = fmaf(wv, xv[j], acc[g][j]);
    }
  }
#pragma unroll
  for (int g = 0; g < 4; ++g)
#pragma unroll
    for (int j = 0; j < 8; ++j) acc[g][j] = wred(acc[g][j]);

  float s0 = 0, s1 = 0, s2 = 0, s3 = 0;
#pragma unroll
  for (int j = 0; j < 8; ++j)
    if (lane == j) { s0 = acc[0][j]; s1 = acc[1][j]; s2 = acc[2][j]; s3 = acc[3][j]; }
  if (lane < 8) {
    const int b = bg + lane;
    s0 += bias[d]; s1 += bias[DD + d]; s2 += bias[2 * DD + d]; s3 += bias[3 * DD + d];
    const float ig = sigm(s0), fg = sigm(s1), gg = tanhf(s2), og = sigm(s3);
    const float cn = fg * cbuf[b * DD + d] + ig * gg;
    const float hv = og * tanhf(cn);
    cbuf[b * DD + d] = cn;
    hnew[b * DD + d] = hv;
  }
}

__device__ __forceinline__ void stage_qw(int gw, int lane, const float* __restrict__ c1,
                                         const float* __restrict__ attn_w,
                                         const float* __restrict__ attn_b,
                                         float* __restrict__ qW) {
  const int d = gw >> 1;
  const int bg = (gw & 1) * 8;
  float acc[8];
#pragma unroll
  for (int j = 0; j < 8; ++j) acc[j] = 0.f;
  for (int kb = 0; kb < 16; ++kb) {
    const int k = kb * 64 + lane;
    const float wv = attn_w[d * 2048 + k];
#pragma unroll
    for (int j = 0; j < 8; ++j) acc[j] = fmaf(wv, c1[(bg + j) * DD + k], acc[j]);
  }
#pragma unroll
  for (int j = 0; j < 8; ++j) acc[j] = wred(acc[j]);
  float sel = 0.f;
#pragma unroll
  for (int j = 0; j < 8; ++j)
    if (lane == j) sel = acc[j];
  if (lane < 8) qW[(bg + lane) * DD + d] = sel + attn_b[d];
}

__device__ __forceinline__ void stage_scores(int gw, int lane, const float* __restrict__ qW,
                                             const float* __restrict__ encWe,
                                             const float* __restrict__ attn_v,
                                             float* __restrict__ scores) {
  const int b = gw >> 7;
  const int s = gw & 127;
  const float* qb = qW + b * DD;
  const float* ew = encWe + ((size_t)(b * SS + s)) * DD;
  float a = 0.f;
  for (int kb = 0; kb < 16; ++kb) {
    const int k = kb * 64 + lane;
    a += attn_v[k] * tanhf(qb[k] + ew[k]);
  }
  a = wred(a);
  if (lane == 0) scores[b * SS + s] = a;
}

__device__ __forceinline__ void stage_weighted(int gw, int lane,
                                               const float* __restrict__ scores,
                                               const float* __restrict__ enc_out,
                                               float* __restrict__ weighted) {
  const int b = gw >> 4;
  const int h = (gw & 15) * 64 + lane;
  float m = -1e30f;
  for (int s = 0; s < SS; ++s) m = fmaxf(m, scores[b * SS + s]);
  float sum = 0.f, acc = 0.f;
  for (int s = 0; s < SS; ++s) {
    const float e = expf(scores[b * SS + s] - m);
    sum += e;
    acc = fmaf(e, enc_out[((size_t)(b * SS + s)) * 1024 + h], acc);
  }
  weighted[b * 1024 + h] = acc / sum;
}

// ---- persistent decoder: prime + 128 steps x 5 barriers ----
__global__ __launch_bounds__(256, 2) void dec_mega_k(
    const float* __restrict__ gs_emb, const float* __restrict__ encWe,
    const float* __restrict__ enc_out, const float* __restrict__ attn_w,
    const float* __restrict__ attn_b, const float* __restrict__ attn_v,
    const float* __restrict__ wih0, const float* __restrict__ whh0,
    const float* __restrict__ b0, const float* __restrict__ wih1,
    const float* __restrict__ whh1, const float* __restrict__ b1,
    float* __restrict__ dh0, float* __restrict__ dc0, float* __restrict__ dh1p,
    float* __restrict__ dc1, float* __restrict__ h1_all, float* __restrict__ qW,
    float* __restrict__ scores, float* __restrict__ weighted,
    const float* __restrict__ zeros, unsigned* bar) {
  const int lane = threadIdx.x & 63;
  const int gw = blockIdx.x * 4 + (threadIdx.x >> 6);  // 0..2047

  // prime: zero state, zero input (writes dh0 slot 1, then dh1p/dc1)
  stage_dec<2 * HH, EE>(gw, lane, zeros, zeros, zeros, dh0 + BB * DD, dc0, wih0, whh0, b0);
  gbar(bar);
  stage_dec<DD, 0>(gw, lane, dh0 + BB * DD, nullptr, zeros, dh1p, dc1, wih1, whh1, b1);
  gbar(bar);

  for (int t = 0; t < TT; ++t) {
    stage_qw(gw, lane, dc1, attn_w, attn_b, qW);
    gbar(bar);
    stage_scores(gw, lane, qW, encWe, attn_v, scores);
    gbar(bar);
    if (gw < 256) stage_weighted(gw, lane, scores, enc_out, weighted);
    gbar(bar);
    const float* x2 = (t == 0) ? zeros : (gs_emb + (size_t)(t - 1) * BB * EE);
    stage_dec<2 * HH, EE>(gw, lane, weighted, x2, dh0 + ((t + 1) & 1) * BB * DD,
                          dh0 + (t & 1) * BB * DD, dc0, wih0, whh0, b0);
    gbar(bar);
    const float* h1prev = (t == 0) ? dh1p : (h1_all + (size_t)(t - 1) * BB * DD);
    stage_dec<DD, 0>(gw, lane, dh0 + (t & 1) * BB * DD, nullptr, h1prev,
                     h1_all + (size_t)t * BB * DD, dc1, wih1, whh1, b1);
    gbar(bar);
  }
}

// ---- encWe[b,s,d] = sum_k enc_out[b,s,k] * attn_w[d, 1024+k]  (once) ----
__global__ void encwe_k(const float* __restrict__ enc_out, const float* __restrict__ attn_w,
                        float* __restrict__ encWe) {
  const int lane = threadIdx.x & 63;
  const int wg = (blockIdx.x * blockDim.x + threadIdx.x) >> 6;
  const int s = wg >> 10;
  const int d = wg & 1023;
  float acc[16];
#pragma unroll
  for (int b = 0; b < 16; ++b) acc[b] = 0.f;
  for (int kb = 0; kb < 16; ++kb) {
    const int k = kb * 64 + lane;
    const float wv = attn_w[(size_t)d * 2048 + 1024 + k];
#pragma unroll
    for (int b = 0; b < 16; ++b)
      acc[b] = fmaf(wv, enc_out[((size_t)(b * SS + s)) * 1024 + k], acc[b]);
  }
#pragma unroll
  for (int b = 0; b < 16; ++b) acc[b] = wred(acc[b]);
  float sel = 0.f;
#pragma unroll
  for (int b = 0; b < 16; ++b)
    if (lane == b) sel = acc[b];
  if (lane < 16) encWe[((size_t)(lane * SS + s)) * 1024 + d] = sel;
}

// ---- all logits at the end ----
__global__ void logits_all_k(const float* __restrict__ h1all, const float* __restrict__ out_w,
                             const float* __restrict__ out_b, float* __restrict__ out) {
  const int lane = threadIdx.x & 63;
  const int t = blockIdx.x;
  const int o = blockIdx.y * 4 + (threadIdx.x >> 6);
  const float* h1 = h1all + (size_t)t * (BB * DD);
  float acc[16];
#pragma unroll
  for (int b = 0; b < 16; ++b) acc[b] = 0.f;
  for (int kb = 0; kb < 16; ++kb) {
    const int k = kb * 64 + lane;
    const float wv = out_w[(size_t)o * DD + k];
#pragma unroll
    for (int b = 0; b < 16; ++b) acc[b] = fmaf(wv, h1[b * DD + k], acc[b]);
  }
#pragma unroll
  for (int b = 0; b < 16; ++b) acc[b] = wred(acc[b]);
  float sel = 0.f;
#pragma unroll
  for (int b = 0; b < 16; ++b)
    if (lane == b) sel = acc[b];
  if (lane < 16) out[(size_t)lane * TT * VO + (size_t)t * VO + o] = sel + out_b[o];
}

extern "C" void kernel_launch(void* const* d_in, const int* in_sizes, int n_in,
                              void* d_out, int out_size, void* d_ws, size_t ws_size,
                              hipStream_t stream) {
  const int* x = (const int*)d_in[0];
  const int* gs = (const int*)d_in[1];
  const float* in_emb = (const float*)d_in[2];
  const float* out_emb = (const float*)d_in[3];
  const float* ewih0 = (const float*)d_in[4];
  const float* ewhh0 = (const float*)d_in[5];
  const float* eb0 = (const float*)d_in[6];
  const float* ewih1 = (const float*)d_in[7];
  const float* ewhh1 = (const float*)d_in[8];
  const float* eb1 = (const float*)d_in[9];
  const float* dwih0 = (const float*)d_in[10];
  const float* dwhh0 = (const float*)d_in[11];
  const float* db0 = (const float*)d_in[12];
  const float* dwih1 = (const float*)d_in[13];
  const float* dwhh1 = (const float*)d_in[14];
  const float* db1 = (const float*)d_in[15];
  const float* attn_w = (const float*)d_in[16];
  const float* attn_b = (const float*)d_in[17];
  const float* attn_v = (const float*)d_in[18];
  const float* out_w = (const float*)d_in[19];
  const float* out_b = (const float*)d_in[20];
  float* out = (float*)d_out;

  float* ws = (float*)d_ws;
  size_t off = 0;
  auto alloc = [&](size_t n) { float* p = ws + off; off += n; return p; };
  // ---- memset-every-call region ----
  unsigned* bar = (unsigned*)alloc(1056);          // two-level barrier counters + gen
  float* h0e = alloc(2 * 2 * BB * HH);             // enc L0 h ping-pong [slot][dir][b][h]
  float* c0e = alloc(2 * BB * HH);
  float* h1e = alloc(2 * 2 * BB * HH);             // enc L1
  float* c1e = alloc(2 * BB * HH);
  float* dh0 = alloc(2 * BB * DD);                 // dec L0 h ping-pong
  float* dc0 = alloc(BB * DD);
  float* dh1p = alloc(BB * DD);                    // primed dec L1 h
  float* dc1 = alloc(BB * DD);
  float* zeros = alloc(BB * DD);
  const size_t state_n = off;
  // ---- fully-overwritten buffers ----
  float* xs_emb = alloc((size_t)SS * BB * EE);
  float* gs_emb = alloc((size_t)TT * BB * EE);
  float* l0 = alloc((size_t)SS * BB * (2 * HH));
  float* enc_out = alloc((size_t)BB * SS * (2 * HH));
  float* encWe = alloc((size_t)BB * SS * DD);
  float* gxA = alloc(2ull * 2048ull * 2048ull);    // x-part gates, reused L0/L1
  float* h1_all = alloc((size_t)TT * BB * DD);
  float* qW = alloc(BB * DD);
  float* scores = alloc(BB * SS);
  float* weighted = alloc(BB * (2 * HH));
  (void)ws_size; (void)in_sizes; (void)n_in; (void)out_size;

  hipMemsetAsync(d_ws, 0, state_n * sizeof(float), stream);

  gather_k<<<dim3(SS, BB), 128, 0, stream>>>(x, in_emb, xs_emb, SS);
  gather_k<<<dim3(TT, BB), 128, 0, stream>>>(gs, out_emb, gs_emb, TT);

  // encoder layer 0: parallel x-part, then persistent recurrence
  gemv16_k<EE><<<dim3(512, 128, 2), 256, 0, stream>>>(
      xs_emb, EE, ewih0, EE, gxA, 2048, (size_t)4 * HH * EE, 2048ull * 2048ull);
  enc_mega_k<<<NBLK, 256, 0, stream>>>(gxA, ewhh0, eb0, h0e, c0e, l0, BB * 2 * HH, 2 * HH,
                                       bar);
  // encoder layer 1
  gemv16_k<2 * HH><<<dim3(512, 128, 2), 256, 0, stream>>>(
      l0, 2 * HH, ewih1, 2 * HH, gxA, 2048, (size_t)4 * HH * 2 * HH, 2048ull * 2048ull);
  enc_mega_k<<<NBLK, 256, 0, stream>>>(gxA, ewhh1, eb1, h1e, c1e, enc_out, 2 * HH,
                                       SS * 2 * HH, bar);
  // step-invariant attention term
  encwe_k<<<32768, 256, 0, stream>>>(enc_out, attn_w, encWe);

  // persistent decoder (prime + 128 steps)
  dec_mega_k<<<NBLK, 256, 0, stream>>>(gs_emb, encWe, enc_out, attn_w, attn_b, attn_v,
                                       dwih0, dwhh0, db0, dwih1, dwhh1, db1, dh0, dc0,
                                       dh1p, dc1, h1_all, qW, scores, weighted, zeros, bar);

  // all logits in one parallel launch
  logits_all_k<<<dim3(TT, VO / 4), 256, 0, stream>>>(h1_all, out_w, out_b, out);
}

// Round 4
// 83997.351 us; speedup vs baseline: 1.2914x; 1.2914x over previous
//
#include <hip/hip_runtime.h>

#define BB 16
#define SS 128
#define TT 128
#define EE 512
#define HH 512
#define DD 1024
#define VO 10000
#define NBLK 512

__device__ __forceinline__ float wred(float s) {
#pragma unroll
  for (int off = 32; off >= 1; off >>= 1) s += __shfl_xor(s, off, 64);
  return s;
}
__device__ __forceinline__ float wmax(float s) {
#pragma unroll
  for (int off = 32; off >= 1; off >>= 1) s = fmaxf(s, __shfl_xor(s, off, 64));
  return s;
}
__device__ __forceinline__ float sigm(float x) { return 1.f / (1.f + expf(-x)); }

// ---- two-level grid barrier; RELAXED spin, ONE release + ONE acquire per block ----
__device__ __forceinline__ void gbar(unsigned* bar) {
  __syncthreads();
  if (threadIdx.x == 0) {
    unsigned* leaf = bar + ((blockIdx.x >> 3) << 4);
    unsigned* root = bar + 1024;
    unsigned* gen = bar + 1040;
    const unsigned g = __hip_atomic_load(gen, __ATOMIC_RELAXED, __HIP_MEMORY_SCOPE_AGENT);
    const unsigned a =
        __hip_atomic_fetch_add(leaf, 1u, __ATOMIC_RELEASE, __HIP_MEMORY_SCOPE_AGENT);
    if (a == 7u) {
      __hip_atomic_store(leaf, 0u, __ATOMIC_RELAXED, __HIP_MEMORY_SCOPE_AGENT);
      const unsigned r =
          __hip_atomic_fetch_add(root, 1u, __ATOMIC_ACQ_REL, __HIP_MEMORY_SCOPE_AGENT);
      if (r == 63u) {
        __hip_atomic_store(root, 0u, __ATOMIC_RELAXED, __HIP_MEMORY_SCOPE_AGENT);
        __hip_atomic_store(gen, g + 1u, __ATOMIC_RELEASE, __HIP_MEMORY_SCOPE_AGENT);
      }
    }
    while (__hip_atomic_load(gen, __ATOMIC_RELAXED, __HIP_MEMORY_SCOPE_AGENT) == g)
      __builtin_amdgcn_s_sleep(8);
    (void)__hip_atomic_load(gen, __ATOMIC_ACQUIRE, __HIP_MEMORY_SCOPE_AGENT);
  }
  __syncthreads();
}

// ---- embedding gather (padding_idx=0 -> zeros), out layout [Sn][B][E] ----
__global__ void gather_k(const int* __restrict__ idx, const float* __restrict__ emb,
                         float* __restrict__ out, int Sn) {
  const int s = blockIdx.x, b = blockIdx.y, tid = threadIdx.x;
  const int id = idx[b * Sn + s];
  float4 v = make_float4(0.f, 0.f, 0.f, 0.f);
  if (id != 0) v = ((const float4*)(emb + (size_t)id * EE))[tid];
  ((float4*)(out + ((size_t)s * BB + b) * EE))[tid] = v;
}

// ---- G[z][n][m] = sum_k X[m,k]*W[z,n,k]  (x-part gate GEMMs, parallel) ----
template <int K>
__global__ void gemv16_k(const float* __restrict__ X, int ldx,
                         const float* __restrict__ W, int ldw,
                         float* __restrict__ G, int M, size_t wz, size_t gz) {
  const int lane = threadIdx.x & 63;
  const int n = blockIdx.x * 4 + (threadIdx.x >> 6);
  const int mg = blockIdx.y;
  const int z = blockIdx.z;
  const float* Xr = X + (size_t)mg * 16 * ldx;
  const float* Wn = W + (size_t)z * wz + (size_t)n * ldw;
  float acc[16];
#pragma unroll
  for (int j = 0; j < 16; ++j) acc[j] = 0.f;
  for (int kb = 0; kb < K / 64; ++kb) {
    const int k = kb * 64 + lane;
    const float wv = Wn[k];
#pragma unroll
    for (int j = 0; j < 16; ++j) acc[j] = fmaf(wv, Xr[(size_t)j * ldx + k], acc[j]);
  }
#pragma unroll
  for (int j = 0; j < 16; ++j) acc[j] = wred(acc[j]);
  float sel = 0.f;
#pragma unroll
  for (int j = 0; j < 16; ++j)
    if (lane == j) sel = acc[j];
  if (lane < 16) G[(size_t)z * gz + (size_t)n * M + mg * 16 + lane] = sel;
}

// ---- persistent encoder layer: whh in VGPRs, c in regs, 1 barrier/step ----
__global__ __launch_bounds__(256, 2) void enc_mega2_k(
    const float* __restrict__ gx, const float* __restrict__ whh,
    const float* __restrict__ bias, float* __restrict__ hbuf, float* __restrict__ seq,
    int seq_ts, int seq_bs, unsigned* bar) {
  const int tid = threadIdx.x, lane = tid & 63, lw = tid >> 6;
  const int gw = blockIdx.x * 4 + lw;          // 0..2047
  const int dir = gw >> 10, r = gw & 1023;
  const int d = r >> 1, gp = r & 1;            // even wave: gates 0(i),2(g); odd: 1(f),3(o)
  const int g0 = gp, g1 = gp + 2;
  const int pair = lw >> 1;
  __shared__ float xch[2][4][16];

  float w[2][8];
  const float* wsrc = whh + (size_t)dir * (4 * HH * HH);
#pragma unroll
  for (int j = 0; j < 8; ++j) {
    w[0][j] = wsrc[(size_t)(g0 * HH + d) * HH + j * 64 + lane];
    w[1][j] = wsrc[(size_t)(g1 * HH + d) * HH + j * 64 + lane];
  }
  const float bv0 = bias[dir * 4 * HH + g0 * HH + d];
  const float bv1 = bias[dir * 4 * HH + g1 * HH + d];
  const float* gxz = gx + (size_t)dir * ((size_t)4 * HH * 2048);
  float creg = 0.f;

  for (int t = 0; t < SS; ++t) {
    const int idx = dir ? (SS - 1 - t) : t;
    const float* hp = hbuf + (t & 1) * (2 * BB * HH) + dir * (BB * HH);
    float* hn = hbuf + (((t & 1) ^ 1)) * (2 * BB * HH) + dir * (BB * HH);
    float a0[16], a1[16];
#pragma unroll
    for (int b = 0; b < 16; ++b) { a0[b] = 0.f; a1[b] = 0.f; }
#pragma unroll
    for (int kb = 0; kb < 8; ++kb) {
      const int k = kb * 64 + lane;
#pragma unroll
      for (int b = 0; b < 16; ++b) {
        const float xv = hp[b * HH + k];
        a0[b] = fmaf(w[0][kb], xv, a0[b]);
        a1[b] = fmaf(w[1][kb], xv, a1[b]);
      }
    }
#pragma unroll
    for (int b = 0; b < 16; ++b) { a0[b] = wred(a0[b]); a1[b] = wred(a1[b]); }
    float s0 = 0.f, s1 = 0.f;
#pragma unroll
    for (int j = 0; j < 16; ++j)
      if (lane == j) { s0 = a0[j]; s1 = a1[j]; }
    if (lane < 16) {
      const int m = idx * 16 + lane;
      xch[pair][g0][lane] = s0 + bv0 + gxz[(size_t)(g0 * HH + d) * 2048 + m];
      xch[pair][g1][lane] = s1 + bv1 + gxz[(size_t)(g1 * HH + d) * 2048 + m];
    }
    __syncthreads();
    if (gp == 0 && lane < 16) {
      const float gi = sigm(xch[pair][0][lane]);
      const float gf = sigm(xch[pair][1][lane]);
      const float gg = tanhf(xch[pair][2][lane]);
      const float go = sigm(xch[pair][3][lane]);
      const float cn = gf * creg + gi * gg;
      creg = cn;
      const float hv = go * tanhf(cn);
      hn[lane * HH + d] = hv;
      seq[(size_t)idx * seq_ts + (size_t)lane * seq_bs + dir * HH + d] = hv;
    }
    gbar(bar);
  }
}

// ---- persistent decoder: all weights in VGPRs, LDS attn slices, 5 barriers/step ----
__global__ __launch_bounds__(256, 2) void dec_mega2_k(
    const float* __restrict__ gs_emb, const float* __restrict__ encWe,
    const float* __restrict__ enc_out, const float* __restrict__ attn_w,
    const float* __restrict__ attn_b, const float* __restrict__ attn_v,
    const float* __restrict__ wih0, const float* __restrict__ whh0,
    const float* __restrict__ b0, const float* __restrict__ wih1,
    const float* __restrict__ whh1, const float* __restrict__ b1,
    const float* __restrict__ zeros, float* __restrict__ dh0, float* __restrict__ h1p,
    float* __restrict__ c1g, float* __restrict__ h1_all, float* __restrict__ qWg,
    float* __restrict__ scoresg, float* __restrict__ wtd, unsigned* bar) {
  const int tid = threadIdx.x, lane = tid & 63, lw = tid >> 6;
  const int gw = blockIdx.x * 4 + lw;  // 0..2047
  const int d = gw >> 1, gp = gw & 1;  // even wave: gates i,g; odd: f,o
  const int g0 = gp, g1 = gp + 2;
  const int pair = lw >> 1;
  const int b_a = blockIdx.x >> 5, jb = blockIdx.x & 31;  // attention mapping

  __shared__ float encWe_s[4][1024];  // s-rows jb*4..+3 of batch b_a
  __shared__ float enc_s[128][33];    // enc_out[b_a][all s][jb*32..+32], padded
  __shared__ float xch[2][4][16];

  // ---- resident weights ----
  float w0[2][40], w1[2][32], wq[16];
#pragma unroll
  for (int kb = 0; kb < 24; ++kb) {
    w0[0][kb] = wih0[(size_t)(g0 * DD + d) * 1536 + kb * 64 + lane];
    w0[1][kb] = wih0[(size_t)(g1 * DD + d) * 1536 + kb * 64 + lane];
  }
#pragma unroll
  for (int kb = 24; kb < 40; ++kb) {
    w0[0][kb] = whh0[(size_t)(g0 * DD + d) * 1024 + (kb - 24) * 64 + lane];
    w0[1][kb] = whh0[(size_t)(g1 * DD + d) * 1024 + (kb - 24) * 64 + lane];
  }
#pragma unroll
  for (int kb = 0; kb < 16; ++kb) {
    w1[0][kb] = wih1[(size_t)(g0 * DD + d) * 1024 + kb * 64 + lane];
    w1[1][kb] = wih1[(size_t)(g1 * DD + d) * 1024 + kb * 64 + lane];
  }
#pragma unroll
  for (int kb = 16; kb < 32; ++kb) {
    w1[0][kb] = whh1[(size_t)(g0 * DD + d) * 1024 + (kb - 16) * 64 + lane];
    w1[1][kb] = whh1[(size_t)(g1 * DD + d) * 1024 + (kb - 16) * 64 + lane];
  }
#pragma unroll
  for (int kb = 0; kb < 16; ++kb) wq[kb] = attn_w[(size_t)d * 2048 + kb * 64 + lane];
  const float bd00 = b0[g0 * DD + d], bd01 = b0[g1 * DD + d];
  const float bd10 = b1[g0 * DD + d], bd11 = b1[g1 * DD + d];
  const float abv = attn_b[d];
  float c0reg = 0.f, c1reg = 0.f;

  // ---- LDS fill (read-only for the whole decode) ----
  for (int i = tid; i < 4 * 1024; i += 256)
    encWe_s[i >> 10][i & 1023] =
        encWe[((size_t)(b_a * SS + jb * 4 + (i >> 10))) * 1024 + (i & 1023)];
  for (int i = tid; i < 128 * 32; i += 256)
    enc_s[i >> 5][i & 31] = enc_out[((size_t)(b_a * SS + (i >> 5))) * 1024 + jb * 32 + (i & 31)];
  __syncthreads();

  // ---- stage lambdas ----
  auto dec0_stage = [&](const float* wv, const float* em, const float* hp, float* hn) {
#pragma unroll 1
    for (int half = 0; half < 2; ++half) {
      const int bb = half * 8;
      float acc0[8], acc1[8];
#pragma unroll
      for (int j = 0; j < 8; ++j) { acc0[j] = 0.f; acc1[j] = 0.f; }
#pragma unroll
      for (int kb = 0; kb < 40; ++kb) {
        const int k = kb * 64 + lane;
#pragma unroll
        for (int j = 0; j < 8; ++j) {
          const float xv = (kb < 16)   ? wv[(bb + j) * 1024 + k]
                           : (kb < 24) ? em[(bb + j) * 512 + (k - 1024)]
                                       : hp[(bb + j) * 1024 + (k - 1536)];
          acc0[j] = fmaf(w0[0][kb], xv, acc0[j]);
          acc1[j] = fmaf(w0[1][kb], xv, acc1[j]);
        }
      }
#pragma unroll
      for (int j = 0; j < 8; ++j) { acc0[j] = wred(acc0[j]); acc1[j] = wred(acc1[j]); }
      float s0 = 0.f, s1 = 0.f;
#pragma unroll
      for (int j = 0; j < 8; ++j)
        if (lane == j) { s0 = acc0[j]; s1 = acc1[j]; }
      if (lane < 8) {
        xch[pair][g0][bb + lane] = s0 + bd00;
        xch[pair][g1][bb + lane] = s1 + bd01;
      }
    }
    __syncthreads();
    if (gp == 0 && lane < 16) {
      const float gi = sigm(xch[pair][0][lane]);
      const float gf = sigm(xch[pair][1][lane]);
      const float gg = tanhf(xch[pair][2][lane]);
      const float go = sigm(xch[pair][3][lane]);
      const float cn = gf * c0reg + gi * gg;
      c0reg = cn;
      hn[lane * 1024 + d] = go * tanhf(cn);
    }
  };

  auto dec1_stage = [&](const float* h0, const float* h1prev, float* h1out) {
#pragma unroll 1
    for (int half = 0; half < 2; ++half) {
      const int bb = half * 8;
      float acc0[8], acc1[8];
#pragma unroll
      for (int j = 0; j < 8; ++j) { acc0[j] = 0.f; acc1[j] = 0.f; }
#pragma unroll
      for (int kb = 0; kb < 32; ++kb) {
        const int k = kb * 64 + lane;
#pragma unroll
        for (int j = 0; j < 8; ++j) {
          const float xv = (kb < 16) ? h0[(bb + j) * 1024 + k]
                                     : h1prev[(bb + j) * 1024 + (k - 1024)];
          acc0[j] = fmaf(w1[0][kb], xv, acc0[j]);
          acc1[j] = fmaf(w1[1][kb], xv, acc1[j]);
        }
      }
#pragma unroll
      for (int j = 0; j < 8; ++j) { acc0[j] = wred(acc0[j]); acc1[j] = wred(acc1[j]); }
      float s0 = 0.f, s1 = 0.f;
#pragma unroll
      for (int j = 0; j < 8; ++j)
        if (lane == j) { s0 = acc0[j]; s1 = acc1[j]; }
      if (lane < 8) {
        xch[pair][g0][bb + lane] = s0 + bd10;
        xch[pair][g1][bb + lane] = s1 + bd11;
      }
    }
    __syncthreads();
    if (gp == 0 && lane < 16) {
      const float gi = sigm(xch[pair][0][lane]);
      const float gf = sigm(xch[pair][1][lane]);
      const float gg = tanhf(xch[pair][2][lane]);
      const float go = sigm(xch[pair][3][lane]);
      const float cn = gf * c1reg + gi * gg;
      c1reg = cn;
      c1g[lane * 1024 + d] = cn;
      h1out[lane * 1024 + d] = go * tanhf(cn);
    }
  };

  auto qw_stage = [&]() {
    const int boff = gp * 8;
    float acc[8];
#pragma unroll
    for (int j = 0; j < 8; ++j) acc[j] = 0.f;
#pragma unroll
    for (int kb = 0; kb < 16; ++kb) {
      const int k = kb * 64 + lane;
#pragma unroll
      for (int j = 0; j < 8; ++j) acc[j] = fmaf(wq[kb], c1g[(boff + j) * 1024 + k], acc[j]);
    }
#pragma unroll
    for (int j = 0; j < 8; ++j) acc[j] = wred(acc[j]);
    float sel = 0.f;
#pragma unroll
    for (int j = 0; j < 8; ++j)
      if (lane == j) sel = acc[j];
    if (lane < 8) qWg[(boff + lane) * 1024 + d] = sel + abv;
  };

  auto scores_stage = [&]() {
    const int sj = jb * 4 + lw;
    float a = 0.f;
#pragma unroll
    for (int kb = 0; kb < 16; ++kb) {
      const int k = kb * 64 + lane;
      a += attn_v[k] * tanhf(qWg[b_a * 1024 + k] + encWe_s[lw][k]);
    }
    a = wred(a);
    if (lane == 0) scoresg[b_a * SS + sj] = a;
  };

  auto smw_stage = [&]() {
    const float sc0 = scoresg[b_a * SS + lane];
    const float sc1 = scoresg[b_a * SS + 64 + lane];
    const float m = wmax(fmaxf(sc0, sc1));
    const float e0 = expf(sc0 - m), e1 = expf(sc1 - m);
    const float inv = 1.f / wred(e0 + e1);
#pragma unroll
    for (int hh = 0; hh < 8; ++hh) {
      const int hcol = lw * 8 + hh;
      float p = e0 * enc_s[lane][hcol] + e1 * enc_s[64 + lane][hcol];
      p = wred(p);
      if (lane == 0) wtd[b_a * 1024 + jb * 32 + hcol] = p * inv;
    }
  };

  // ---- priming (zero state, zero input) ----
  dec0_stage(zeros, zeros, zeros, dh0);
  gbar(bar);
  dec1_stage(dh0, zeros, h1p);
  gbar(bar);

  // ---- decode loop ----
  for (int t = 0; t < TT; ++t) {
    qw_stage();
    gbar(bar);
    scores_stage();
    gbar(bar);
    smw_stage();
    gbar(bar);
    const float* em = t ? gs_emb + (size_t)(t - 1) * BB * EE : zeros;
    dec0_stage(wtd, em, dh0 + (t & 1) * (BB * DD), dh0 + ((t & 1) ^ 1) * (BB * DD));
    gbar(bar);
    const float* h1prev = t ? h1_all + (size_t)(t - 1) * (BB * DD) : h1p;
    dec1_stage(dh0 + ((t & 1) ^ 1) * (BB * DD), h1prev, h1_all + (size_t)t * (BB * DD));
    gbar(bar);
  }
}

// ---- encWe[b,s,d] = sum_k enc_out[b,s,k] * attn_w[d, 1024+k]  (once) ----
__global__ void encwe_k(const float* __restrict__ enc_out, const float* __restrict__ attn_w,
                        float* __restrict__ encWe) {
  const int lane = threadIdx.x & 63;
  const int wg = (blockIdx.x * blockDim.x + threadIdx.x) >> 6;
  const int s = wg >> 10;
  const int d = wg & 1023;
  float acc[16];
#pragma unroll
  for (int b = 0; b < 16; ++b) acc[b] = 0.f;
  for (int kb = 0; kb < 16; ++kb) {
    const int k = kb * 64 + lane;
    const float wv = attn_w[(size_t)d * 2048 + 1024 + k];
#pragma unroll
    for (int b = 0; b < 16; ++b)
      acc[b] = fmaf(wv, enc_out[((size_t)(b * SS + s)) * 1024 + k], acc[b]);
  }
#pragma unroll
  for (int b = 0; b < 16; ++b) acc[b] = wred(acc[b]);
  float sel = 0.f;
#pragma unroll
  for (int b = 0; b < 16; ++b)
    if (lane == b) sel = acc[b];
  if (lane < 16) encWe[((size_t)(lane * SS + s)) * 1024 + d] = sel;
}

// ---- all logits at the end ----
__global__ void logits_all_k(const float* __restrict__ h1all, const float* __restrict__ out_w,
                             const float* __restrict__ out_b, float* __restrict__ out) {
  const int lane = threadIdx.x & 63;
  const int t = blockIdx.x;
  const int o = blockIdx.y * 4 + (threadIdx.x >> 6);
  const float* h1 = h1all + (size_t)t * (BB * DD);
  float acc[16];
#pragma unroll
  for (int b = 0; b < 16; ++b) acc[b] = 0.f;
  for (int kb = 0; kb < 16; ++kb) {
    const int k = kb * 64 + lane;
    const float wv = out_w[(size_t)o * DD + k];
#pragma unroll
    for (int b = 0; b < 16; ++b) acc[b] = fmaf(wv, h1[b * DD + k], acc[b]);
  }
#pragma unroll
  for (int b = 0; b < 16; ++b) acc[b] = wred(acc[b]);
  float sel = 0.f;
#pragma unroll
  for (int b = 0; b < 16; ++b)
    if (lane == b) sel = acc[b];
  if (lane < 16) out[(size_t)lane * TT * VO + (size_t)t * VO + o] = sel + out_b[o];
}

extern "C" void kernel_launch(void* const* d_in, const int* in_sizes, int n_in,
                              void* d_out, int out_size, void* d_ws, size_t ws_size,
                              hipStream_t stream) {
  const int* x = (const int*)d_in[0];
  const int* gs = (const int*)d_in[1];
  const float* in_emb = (const float*)d_in[2];
  const float* out_emb = (const float*)d_in[3];
  const float* ewih0 = (const float*)d_in[4];
  const float* ewhh0 = (const float*)d_in[5];
  const float* eb0 = (const float*)d_in[6];
  const float* ewih1 = (const float*)d_in[7];
  const float* ewhh1 = (const float*)d_in[8];
  const float* eb1 = (const float*)d_in[9];
  const float* dwih0 = (const float*)d_in[10];
  const float* dwhh0 = (const float*)d_in[11];
  const float* db0 = (const float*)d_in[12];
  const float* dwih1 = (const float*)d_in[13];
  const float* dwhh1 = (const float*)d_in[14];
  const float* db1 = (const float*)d_in[15];
  const float* attn_w = (const float*)d_in[16];
  const float* attn_b = (const float*)d_in[17];
  const float* attn_v = (const float*)d_in[18];
  const float* out_w = (const float*)d_in[19];
  const float* out_b = (const float*)d_in[20];
  float* out = (float*)d_out;

  float* ws = (float*)d_ws;
  size_t off = 0;
  auto alloc = [&](size_t n) { float* p = ws + off; off += n; return p; };
  // ---- memset-every-call region ----
  unsigned* bar = (unsigned*)alloc(1056);        // barrier counters + gen
  float* h0e = alloc(2 * 2 * BB * HH);           // enc L0 h ping-pong [slot][dir][b][h]
  float* h1e = alloc(2 * 2 * BB * HH);           // enc L1
  float* dh0 = alloc(2 * BB * DD);               // dec L0 h ping-pong
  float* dh1p = alloc(BB * DD);                  // primed dec L1 h
  float* dc1g = alloc(BB * DD);                  // dec L1 c (global copy for qw)
  float* zeros = alloc(BB * 1536);
  const size_t state_n = off;
  // ---- fully-overwritten buffers ----
  float* xs_emb = alloc((size_t)SS * BB * EE);
  float* gs_emb = alloc((size_t)TT * BB * EE);
  float* l0 = alloc((size_t)SS * BB * (2 * HH));
  float* enc_out = alloc((size_t)BB * SS * (2 * HH));
  float* encWe = alloc((size_t)BB * SS * DD);
  float* gxA = alloc(2ull * 2048ull * 2048ull);  // x-part gates, reused L0/L1
  float* h1_all = alloc((size_t)TT * BB * DD);
  float* qW = alloc(BB * DD);
  float* scores = alloc(BB * SS);
  float* wtd = alloc(BB * DD);
  (void)ws_size; (void)in_sizes; (void)n_in; (void)out_size;

  hipMemsetAsync(d_ws, 0, state_n * sizeof(float), stream);

  gather_k<<<dim3(SS, BB), 128, 0, stream>>>(x, in_emb, xs_emb, SS);
  gather_k<<<dim3(TT, BB), 128, 0, stream>>>(gs, out_emb, gs_emb, TT);

  // encoder layer 0: parallel x-part, then persistent recurrence
  gemv16_k<EE><<<dim3(512, 128, 2), 256, 0, stream>>>(
      xs_emb, EE, ewih0, EE, gxA, 2048, (size_t)4 * HH * EE, 2048ull * 2048ull);
  enc_mega2_k<<<NBLK, 256, 0, stream>>>(gxA, ewhh0, eb0, h0e, l0, BB * 2 * HH, 2 * HH, bar);
  // encoder layer 1
  gemv16_k<2 * HH><<<dim3(512, 128, 2), 256, 0, stream>>>(
      l0, 2 * HH, ewih1, 2 * HH, gxA, 2048, (size_t)4 * HH * 2 * HH, 2048ull * 2048ull);
  enc_mega2_k<<<NBLK, 256, 0, stream>>>(gxA, ewhh1, eb1, h1e, enc_out, 2 * HH, SS * 2 * HH,
                                        bar);
  // step-invariant attention term
  encwe_k<<<32768, 256, 0, stream>>>(enc_out, attn_w, encWe);

  // persistent decoder (prime + 128 steps)
  dec_mega2_k<<<NBLK, 256, 0, stream>>>(gs_emb, encWe, enc_out, attn_w, attn_b, attn_v,
                                        dwih0, dwhh0, db0, dwih1, dwhh1, db1, zeros, dh0,
                                        dh1p, dc1g, h1_all, qW, scores, wtd, bar);

  // all logits in one parallel launch
  logits_all_k<<<dim3(TT, VO / 4), 256, 0, stream>>>(h1_all, out_w, out_b, out);
}

// Round 5
// 66723.456 us; speedup vs baseline: 1.6257x; 1.2589x over previous
//
#include <hip/hip_runtime.h>

#define BB 16
#define SS 128
#define TT 128
#define EE 512
#define HH 512
#define DD 1024
#define VO 10000
#define NBLK 256   // one persistent block per CU
#define NTHR 512   // 8 waves

__device__ __forceinline__ float wred(float s) {
#pragma unroll
  for (int off = 32; off >= 1; off >>= 1) s += __shfl_xor(s, off, 64);
  return s;
}
__device__ __forceinline__ float wmax(float s) {
#pragma unroll
  for (int off = 32; off >= 1; off >>= 1) s = fmaxf(s, __shfl_xor(s, off, 64));
  return s;
}
__device__ __forceinline__ float sigm(float x) { return 1.f / (1.f + expf(-x)); }

// ---- two-level grid barrier, generation-counted, per-domain ----
// domain layout (uints): leaves at [(lb>>3)<<5] (128B apart), root at [1536],
// gen at [1568]. Domain stride 2048 uints. ACQ_REL on leaf+root adds builds the
// release chain: every block's writes -> leaf winner -> root winner -> gen
// release; waiters sync via final ACQUIRE of gen.
__device__ __forceinline__ void gbar(unsigned* bar, int lb, unsigned nleaf) {
  __syncthreads();
  if (threadIdx.x == 0) {
    unsigned* leaf = bar + ((lb >> 3) << 5);
    unsigned* root = bar + 1536;
    unsigned* gen = bar + 1568;
    const unsigned g = __hip_atomic_load(gen, __ATOMIC_RELAXED, __HIP_MEMORY_SCOPE_AGENT);
    const unsigned a =
        __hip_atomic_fetch_add(leaf, 1u, __ATOMIC_ACQ_REL, __HIP_MEMORY_SCOPE_AGENT);
    if (a == 7u) {
      __hip_atomic_store(leaf, 0u, __ATOMIC_RELAXED, __HIP_MEMORY_SCOPE_AGENT);
      const unsigned r =
          __hip_atomic_fetch_add(root, 1u, __ATOMIC_ACQ_REL, __HIP_MEMORY_SCOPE_AGENT);
      if (r == nleaf - 1u) {
        __hip_atomic_store(root, 0u, __ATOMIC_RELAXED, __HIP_MEMORY_SCOPE_AGENT);
        __hip_atomic_store(gen, g + 1u, __ATOMIC_RELEASE, __HIP_MEMORY_SCOPE_AGENT);
      }
    }
    while (__hip_atomic_load(gen, __ATOMIC_RELAXED, __HIP_MEMORY_SCOPE_AGENT) == g)
      __builtin_amdgcn_s_sleep(2);
    (void)__hip_atomic_load(gen, __ATOMIC_ACQUIRE, __HIP_MEMORY_SCOPE_AGENT);
  }
  __syncthreads();
}

// ---- embedding gather (padding_idx=0 -> zeros), out layout [Sn][B][E] ----
__global__ void gather_k(const int* __restrict__ idx, const float* __restrict__ emb,
                         float* __restrict__ out, int Sn) {
  const int s = blockIdx.x, b = blockIdx.y, tid = threadIdx.x;
  const int id = idx[b * Sn + s];
  float4 v = make_float4(0.f, 0.f, 0.f, 0.f);
  if (id != 0) v = ((const float4*)(emb + (size_t)id * EE))[tid];
  ((float4*)(out + ((size_t)s * BB + b) * EE))[tid] = v;
}

// ---- G[z][n][m] = sum_k X[m,k]*W[z,n,k]  (x-part gate GEMMs, parallel) ----
template <int K>
__global__ void gemv16_k(const float* __restrict__ X, int ldx,
                         const float* __restrict__ W, int ldw,
                         float* __restrict__ G, int M, size_t wz, size_t gz) {
  const int lane = threadIdx.x & 63;
  const int n = blockIdx.x * 4 + (threadIdx.x >> 6);
  const int mg = blockIdx.y;
  const int z = blockIdx.z;
  const float* Xr = X + (size_t)mg * 16 * ldx;
  const float* Wn = W + (size_t)z * wz + (size_t)n * ldw;
  float acc[16];
#pragma unroll
  for (int j = 0; j < 16; ++j) acc[j] = 0.f;
  for (int kb = 0; kb < K / 64; ++kb) {
    const int k = kb * 64 + lane;
    const float wv = Wn[k];
#pragma unroll
    for (int j = 0; j < 16; ++j) acc[j] = fmaf(wv, Xr[(size_t)j * ldx + k], acc[j]);
  }
#pragma unroll
  for (int j = 0; j < 16; ++j) acc[j] = wred(acc[j]);
  float sel = 0.f;
#pragma unroll
  for (int j = 0; j < 16; ++j)
    if (lane == j) sel = acc[j];
  if (lane < 16) G[(size_t)z * gz + (size_t)n * M + mg * 16 + lane] = sel;
}

// ---- persistent encoder layer: 256 blocks x 512 thr, whh in VGPRs ----
__global__ __launch_bounds__(512, 1) void enc_mega3_k(
    const float* __restrict__ gx, const float* __restrict__ whh,
    const float* __restrict__ bias, float* __restrict__ hbuf, float* __restrict__ seq,
    int seq_ts, int seq_bs, unsigned* __restrict__ barbase) {
  const int tid = threadIdx.x, lane = tid & 63, lw = tid >> 6;
  const int gw = blockIdx.x * 8 + lw;  // 0..2047
  const int dir = gw >> 10, r = gw & 1023;
  const int d = r >> 1, gp = r & 1;  // even wave: gates 0(i),2(g); odd: 1(f),3(o)
  const int g0 = gp, g1 = gp + 2;
  const int pair = lw >> 1;
  unsigned* bar = barbase + dir * 2048;
  const int lb = blockIdx.x & 127;  // block index within dir

  __shared__ float xch[4][4][16];

  float wa[8], wb[8];
  const float* wsrc = whh + (size_t)dir * (4 * HH * HH);
#pragma unroll
  for (int j = 0; j < 8; ++j) {
    wa[j] = wsrc[(size_t)(g0 * HH + d) * HH + j * 64 + lane];
    wb[j] = wsrc[(size_t)(g1 * HH + d) * HH + j * 64 + lane];
  }
  const float bv0 = bias[dir * 4 * HH + g0 * HH + d];
  const float bv1 = bias[dir * 4 * HH + g1 * HH + d];
  const float* gxz = gx + (size_t)dir * ((size_t)4 * HH * 2048);
  float creg = 0.f;

  for (int t = 0; t < SS; ++t) {
    const int idx = dir ? (SS - 1 - t) : t;
    const float* hp = hbuf + (t & 1) * (2 * BB * HH) + dir * (BB * HH);
    float* hn = hbuf + ((t & 1) ^ 1) * (2 * BB * HH) + dir * (BB * HH);
    float a0[16], a1[16];
#pragma unroll
    for (int b = 0; b < 16; ++b) { a0[b] = 0.f; a1[b] = 0.f; }
#pragma unroll
    for (int kb = 0; kb < 8; ++kb) {
      const int k = kb * 64 + lane;
#pragma unroll
      for (int b = 0; b < 16; ++b) {
        const float xv = hp[b * HH + k];
        a0[b] = fmaf(wa[kb], xv, a0[b]);
        a1[b] = fmaf(wb[kb], xv, a1[b]);
      }
    }
#pragma unroll
    for (int b = 0; b < 16; ++b) { a0[b] = wred(a0[b]); a1[b] = wred(a1[b]); }
    float s0 = 0.f, s1 = 0.f;
#pragma unroll
    for (int j = 0; j < 16; ++j)
      if (lane == j) { s0 = a0[j]; s1 = a1[j]; }
    if (lane < 16) {
      const int m = idx * 16 + lane;
      xch[pair][g0][lane] = s0 + bv0 + gxz[(size_t)(g0 * HH + d) * 2048 + m];
      xch[pair][g1][lane] = s1 + bv1 + gxz[(size_t)(g1 * HH + d) * 2048 + m];
    }
    __syncthreads();
    if (gp == 0 && lane < 16) {
      const float gi = sigm(xch[pair][0][lane]);
      const float gf = sigm(xch[pair][1][lane]);
      const float gg = tanhf(xch[pair][2][lane]);
      const float go = sigm(xch[pair][3][lane]);
      const float cn = gf * creg + gi * gg;
      creg = cn;
      const float hv = go * tanhf(cn);
      hn[lane * HH + d] = hv;
      seq[(size_t)idx * seq_ts + (size_t)lane * seq_bs + dir * HH + d] = hv;
    }
    gbar(bar, lb, 16u);
  }
}

// ---- decoder GEMV stages: weights passed as fixed arrays by reference ----
__device__ __forceinline__ void dec0_gemv(int lane, int pair, int g0, int g1,
                                          const float (&wa)[40], const float (&wb)[40],
                                          const float* __restrict__ wv,
                                          const float* __restrict__ em,
                                          const float* __restrict__ hp, float bva, float bvb,
                                          float (*xch)[4][16]) {
#pragma unroll 1
  for (int half = 0; half < 2; ++half) {
    const int bb = half * 8;
    float acc0[8], acc1[8];
#pragma unroll
    for (int j = 0; j < 8; ++j) { acc0[j] = 0.f; acc1[j] = 0.f; }
#pragma unroll
    for (int kb = 0; kb < 16; ++kb) {
      const int k = kb * 64 + lane;
#pragma unroll
      for (int j = 0; j < 8; ++j) {
        const float xv = wv[(bb + j) * 1024 + k];
        acc0[j] = fmaf(wa[kb], xv, acc0[j]);
        acc1[j] = fmaf(wb[kb], xv, acc1[j]);
      }
    }
#pragma unroll
    for (int kb = 0; kb < 8; ++kb) {
      const int k = kb * 64 + lane;
#pragma unroll
      for (int j = 0; j < 8; ++j) {
        const float xv = em[(bb + j) * 512 + k];
        acc0[j] = fmaf(wa[16 + kb], xv, acc0[j]);
        acc1[j] = fmaf(wb[16 + kb], xv, acc1[j]);
      }
    }
#pragma unroll
    for (int kb = 0; kb < 16; ++kb) {
      const int k = kb * 64 + lane;
#pragma unroll
      for (int j = 0; j < 8; ++j) {
        const float xv = hp[(bb + j) * 1024 + k];
        acc0[j] = fmaf(wa[24 + kb], xv, acc0[j]);
        acc1[j] = fmaf(wb[24 + kb], xv, acc1[j]);
      }
    }
#pragma unroll
    for (int j = 0; j < 8; ++j) { acc0[j] = wred(acc0[j]); acc1[j] = wred(acc1[j]); }
    float s0 = 0.f, s1 = 0.f;
#pragma unroll
    for (int j = 0; j < 8; ++j)
      if (lane == j) { s0 = acc0[j]; s1 = acc1[j]; }
    if (lane < 8) {
      xch[pair][g0][bb + lane] = s0 + bva;
      xch[pair][g1][bb + lane] = s1 + bvb;
    }
  }
}

__device__ __forceinline__ void dec1_gemv(int lane, int pair, int g0, int g1,
                                          const float (&wa)[32], const float (&wb)[32],
                                          const float* __restrict__ h0,
                                          const float* __restrict__ h1prev, float bva,
                                          float bvb, float (*xch)[4][16]) {
#pragma unroll 1
  for (int half = 0; half < 2; ++half) {
    const int bb = half * 8;
    float acc0[8], acc1[8];
#pragma unroll
    for (int j = 0; j < 8; ++j) { acc0[j] = 0.f; acc1[j] = 0.f; }
#pragma unroll
    for (int kb = 0; kb < 16; ++kb) {
      const int k = kb * 64 + lane;
#pragma unroll
      for (int j = 0; j < 8; ++j) {
        const float xv = h0[(bb + j) * 1024 + k];
        acc0[j] = fmaf(wa[kb], xv, acc0[j]);
        acc1[j] = fmaf(wb[kb], xv, acc1[j]);
      }
    }
#pragma unroll
    for (int kb = 0; kb < 16; ++kb) {
      const int k = kb * 64 + lane;
#pragma unroll
      for (int j = 0; j < 8; ++j) {
        const float xv = h1prev[(bb + j) * 1024 + k];
        acc0[j] = fmaf(wa[16 + kb], xv, acc0[j]);
        acc1[j] = fmaf(wb[16 + kb], xv, acc1[j]);
      }
    }
#pragma unroll
    for (int j = 0; j < 8; ++j) { acc0[j] = wred(acc0[j]); acc1[j] = wred(acc1[j]); }
    float s0 = 0.f, s1 = 0.f;
#pragma unroll
    for (int j = 0; j < 8; ++j)
      if (lane == j) { s0 = acc0[j]; s1 = acc1[j]; }
    if (lane < 8) {
      xch[pair][g0][bb + lane] = s0 + bva;
      xch[pair][g1][bb + lane] = s1 + bvb;
    }
  }
}

// ---- persistent decoder: 256 blocks x 512 thr, all weights in VGPRs ----
__global__ __launch_bounds__(512, 1) void dec_mega3_k(
    const float* __restrict__ gs_emb, const float* __restrict__ encWe,
    const float* __restrict__ enc_out, const float* __restrict__ attn_w,
    const float* __restrict__ attn_b, const float* __restrict__ attn_v,
    const float* __restrict__ wih0, const float* __restrict__ whh0,
    const float* __restrict__ b0, const float* __restrict__ wih1,
    const float* __restrict__ whh1, const float* __restrict__ b1,
    const float* __restrict__ zeros, float* __restrict__ dh0, float* __restrict__ h1p,
    float* __restrict__ c1g, float* __restrict__ h1_all, float* __restrict__ qWg,
    float* __restrict__ scoresg, float* __restrict__ wtd, unsigned* __restrict__ bar) {
  const int tid = threadIdx.x, lane = tid & 63, lw = tid >> 6;
  const int gw = blockIdx.x * 8 + lw;  // 0..2047
  const int d = gw >> 1, gp = gw & 1;  // even wave: gates i,g; odd: f,o
  const int g0 = gp, g1 = gp + 2;
  const int pair = lw >> 1;
  const int b_a = blockIdx.x >> 4, jb = blockIdx.x & 15;  // attention mapping

  __shared__ float encWe_s[8][1024];  // s-rows jb*8..+7 of batch b_a
  __shared__ float enc_s[128][65];    // enc_out[b_a][all s][jb*64..+63], padded
  __shared__ float av_s[1024];
  __shared__ float xch[4][4][16];

  // ---- resident weights (all constant-indexed, fully unrolled) ----
  float w0a[40], w0b[40], w1a[32], w1b[32], wq[16];
#pragma unroll
  for (int kb = 0; kb < 24; ++kb) {
    w0a[kb] = wih0[(size_t)(g0 * DD + d) * 1536 + kb * 64 + lane];
    w0b[kb] = wih0[(size_t)(g1 * DD + d) * 1536 + kb * 64 + lane];
  }
#pragma unroll
  for (int kb = 0; kb < 16; ++kb) {
    w0a[24 + kb] = whh0[(size_t)(g0 * DD + d) * 1024 + kb * 64 + lane];
    w0b[24 + kb] = whh0[(size_t)(g1 * DD + d) * 1024 + kb * 64 + lane];
  }
#pragma unroll
  for (int kb = 0; kb < 16; ++kb) {
    w1a[kb] = wih1[(size_t)(g0 * DD + d) * 1024 + kb * 64 + lane];
    w1b[kb] = wih1[(size_t)(g1 * DD + d) * 1024 + kb * 64 + lane];
  }
#pragma unroll
  for (int kb = 0; kb < 16; ++kb) {
    w1a[16 + kb] = whh1[(size_t)(g0 * DD + d) * 1024 + kb * 64 + lane];
    w1b[16 + kb] = whh1[(size_t)(g1 * DD + d) * 1024 + kb * 64 + lane];
  }
#pragma unroll
  for (int kb = 0; kb < 16; ++kb) wq[kb] = attn_w[(size_t)d * 2048 + kb * 64 + lane];
  const float bd00 = b0[g0 * DD + d], bd01 = b0[g1 * DD + d];
  const float bd10 = b1[g0 * DD + d], bd11 = b1[g1 * DD + d];
  const float abv = attn_b[d];
  float c0reg = 0.f, c1reg = 0.f;

  // ---- LDS fill (read-only for the whole decode) ----
  for (int i = tid; i < 8 * 1024; i += NTHR)
    encWe_s[i >> 10][i & 1023] =
        encWe[((size_t)(b_a * SS + jb * 8 + (i >> 10))) * 1024 + (i & 1023)];
  for (int i = tid; i < 128 * 64; i += NTHR)
    enc_s[i >> 6][i & 63] = enc_out[((size_t)(b_a * SS + (i >> 6))) * 1024 + jb * 64 + (i & 63)];
  for (int i = tid; i < 1024; i += NTHR) av_s[i] = attn_v[i];
  __syncthreads();

  // ---- priming: layer0 gates = biases (zero input/state) ----
  if (lane < 16) {
    xch[pair][g0][lane] = bd00;
    xch[pair][g1][lane] = bd01;
  }
  __syncthreads();
  if (gp == 0 && lane < 16) {
    const float gi = sigm(xch[pair][0][lane]);
    const float gf = sigm(xch[pair][1][lane]);
    const float gg = tanhf(xch[pair][2][lane]);
    const float go = sigm(xch[pair][3][lane]);
    const float cn = gf * c0reg + gi * gg;
    c0reg = cn;
    dh0[lane * 1024 + d] = go * tanhf(cn);  // slot 0
  }
  gbar(bar, blockIdx.x, 32u);
  dec1_gemv(lane, pair, g0, g1, w1a, w1b, dh0, zeros, bd10, bd11, xch);
  __syncthreads();
  if (gp == 0 && lane < 16) {
    const float gi = sigm(xch[pair][0][lane]);
    const float gf = sigm(xch[pair][1][lane]);
    const float gg = tanhf(xch[pair][2][lane]);
    const float go = sigm(xch[pair][3][lane]);
    const float cn = gf * c1reg + gi * gg;
    c1reg = cn;
    c1g[lane * 1024 + d] = cn;
    h1p[lane * 1024 + d] = go * tanhf(cn);
  }
  gbar(bar, blockIdx.x, 32u);

  // ---- decode loop: 5 barriers per step ----
  for (int t = 0; t < TT; ++t) {
    {  // qW[b,d] = attn_b[d] + c1[b,:]·attn_w[d,:1024]
      const int boff = gp * 8;
      float acc[8];
#pragma unroll
      for (int j = 0; j < 8; ++j) acc[j] = 0.f;
#pragma unroll
      for (int kb = 0; kb < 16; ++kb) {
        const int k = kb * 64 + lane;
#pragma unroll
        for (int j = 0; j < 8; ++j) acc[j] = fmaf(wq[kb], c1g[(boff + j) * 1024 + k], acc[j]);
      }
#pragma unroll
      for (int j = 0; j < 8; ++j) acc[j] = wred(acc[j]);
      float sel = 0.f;
#pragma unroll
      for (int j = 0; j < 8; ++j)
        if (lane == j) sel = acc[j];
      if (lane < 8) qWg[(boff + lane) * 1024 + d] = sel + abv;
    }
    gbar(bar, blockIdx.x, 32u);
    {  // scores[b_a, jb*8+lw]
      const int sj = jb * 8 + lw;
      float a = 0.f;
#pragma unroll
      for (int kb = 0; kb < 16; ++kb) {
        const int k = kb * 64 + lane;
        a += av_s[k] * tanhf(qWg[b_a * 1024 + k] + encWe_s[lw][k]);
      }
      a = wred(a);
      if (lane == 0) scoresg[b_a * SS + sj] = a;
    }
    gbar(bar, blockIdx.x, 32u);
    {  // softmax + weighted sum for h-cols jb*64..+63 of batch b_a
      const float sc0 = scoresg[b_a * SS + lane];
      const float sc1 = scoresg[b_a * SS + 64 + lane];
      const float m = wmax(fmaxf(sc0, sc1));
      const float e0 = expf(sc0 - m), e1 = expf(sc1 - m);
      const float inv = 1.f / wred(e0 + e1);
#pragma unroll
      for (int hh = 0; hh < 8; ++hh) {
        const int hcol = lw * 8 + hh;
        float p = e0 * enc_s[lane][hcol] + e1 * enc_s[64 + lane][hcol];
        p = wred(p);
        if (lane == 0) wtd[b_a * 1024 + jb * 64 + hcol] = p * inv;
      }
    }
    gbar(bar, blockIdx.x, 32u);
    {  // decoder layer 0
      const float* em = t ? gs_emb + (size_t)(t - 1) * BB * EE : zeros;
      dec0_gemv(lane, pair, g0, g1, w0a, w0b, wtd, em, dh0 + (t & 1) * (BB * DD), bd00, bd01,
                xch);
      __syncthreads();
      if (gp == 0 && lane < 16) {
        const float gi = sigm(xch[pair][0][lane]);
        const float gf = sigm(xch[pair][1][lane]);
        const float gg = tanhf(xch[pair][2][lane]);
        const float go = sigm(xch[pair][3][lane]);
        const float cn = gf * c0reg + gi * gg;
        c0reg = cn;
        dh0[((t & 1) ^ 1) * (BB * DD) + lane * 1024 + d] = go * tanhf(cn);
      }
    }
    gbar(bar, blockIdx.x, 32u);
    {  // decoder layer 1
      const float* h1prev = t ? h1_all + (size_t)(t - 1) * (BB * DD) : h1p;
      dec1_gemv(lane, pair, g0, g1, w1a, w1b, dh0 + ((t & 1) ^ 1) * (BB * DD), h1prev, bd10,
                bd11, xch);
      __syncthreads();
      if (gp == 0 && lane < 16) {
        const float gi = sigm(xch[pair][0][lane]);
        const float gf = sigm(xch[pair][1][lane]);
        const float gg = tanhf(xch[pair][2][lane]);
        const float go = sigm(xch[pair][3][lane]);
        const float cn = gf * c1reg + gi * gg;
        c1reg = cn;
        c1g[lane * 1024 + d] = cn;
        h1_all[(size_t)t * (BB * DD) + lane * 1024 + d] = go * tanhf(cn);
      }
    }
    gbar(bar, blockIdx.x, 32u);
  }
}

// ---- encWe[b,s,d] = sum_k enc_out[b,s,k] * attn_w[d, 1024+k]  (once) ----
__global__ void encwe_k(const float* __restrict__ enc_out, const float* __restrict__ attn_w,
                        float* __restrict__ encWe) {
  const int lane = threadIdx.x & 63;
  const int wg = (blockIdx.x * blockDim.x + threadIdx.x) >> 6;
  const int s = wg >> 10;
  const int d = wg & 1023;
  float acc[16];
#pragma unroll
  for (int b = 0; b < 16; ++b) acc[b] = 0.f;
  for (int kb = 0; kb < 16; ++kb) {
    const int k = kb * 64 + lane;
    const float wv = attn_w[(size_t)d * 2048 + 1024 + k];
#pragma unroll
    for (int b = 0; b < 16; ++b)
      acc[b] = fmaf(wv, enc_out[((size_t)(b * SS + s)) * 1024 + k], acc[b]);
  }
#pragma unroll
  for (int b = 0; b < 16; ++b) acc[b] = wred(acc[b]);
  float sel = 0.f;
#pragma unroll
  for (int b = 0; b < 16; ++b)
    if (lane == b) sel = acc[b];
  if (lane < 16) encWe[((size_t)(lane * SS + s)) * 1024 + d] = sel;
}

// ---- all logits at the end ----
__global__ void logits_all_k(const float* __restrict__ h1all, const float* __restrict__ out_w,
                             const float* __restrict__ out_b, float* __restrict__ out) {
  const int lane = threadIdx.x & 63;
  const int t = blockIdx.x;
  const int o = blockIdx.y * 4 + (threadIdx.x >> 6);
  const float* h1 = h1all + (size_t)t * (BB * DD);
  float acc[16];
#pragma unroll
  for (int b = 0; b < 16; ++b) acc[b] = 0.f;
  for (int kb = 0; kb < 16; ++kb) {
    const int k = kb * 64 + lane;
    const float wv = out_w[(size_t)o * DD + k];
#pragma unroll
    for (int b = 0; b < 16; ++b) acc[b] = fmaf(wv, h1[b * DD + k], acc[b]);
  }
#pragma unroll
  for (int b = 0; b < 16; ++b) acc[b] = wred(acc[b]);
  float sel = 0.f;
#pragma unroll
  for (int b = 0; b < 16; ++b)
    if (lane == b) sel = acc[b];
  if (lane < 16) out[(size_t)lane * TT * VO + (size_t)t * VO + o] = sel + out_b[o];
}

extern "C" void kernel_launch(void* const* d_in, const int* in_sizes, int n_in,
                              void* d_out, int out_size, void* d_ws, size_t ws_size,
                              hipStream_t stream) {
  const int* x = (const int*)d_in[0];
  const int* gs = (const int*)d_in[1];
  const float* in_emb = (const float*)d_in[2];
  const float* out_emb = (const float*)d_in[3];
  const float* ewih0 = (const float*)d_in[4];
  const float* ewhh0 = (const float*)d_in[5];
  const float* eb0 = (const float*)d_in[6];
  const float* ewih1 = (const float*)d_in[7];
  const float* ewhh1 = (const float*)d_in[8];
  const float* eb1 = (const float*)d_in[9];
  const float* dwih0 = (const float*)d_in[10];
  const float* dwhh0 = (const float*)d_in[11];
  const float* db0 = (const float*)d_in[12];
  const float* dwih1 = (const float*)d_in[13];
  const float* dwhh1 = (const float*)d_in[14];
  const float* db1 = (const float*)d_in[15];
  const float* attn_w = (const float*)d_in[16];
  const float* attn_b = (const float*)d_in[17];
  const float* attn_v = (const float*)d_in[18];
  const float* out_w = (const float*)d_in[19];
  const float* out_b = (const float*)d_in[20];
  float* out = (float*)d_out;

  float* ws = (float*)d_ws;
  size_t off = 0;
  auto alloc = [&](size_t n) { float* p = ws + off; off += n; return p; };
  // ---- memset-every-call region ----
  unsigned* bar = (unsigned*)alloc(3 * 2048);    // 3 barrier domains (encd0, encd1, dec)
  float* h0e = alloc(2 * 2 * BB * HH);           // enc L0 h ping-pong [slot][dir][b][h]
  float* h1e = alloc(2 * 2 * BB * HH);           // enc L1
  float* dh0 = alloc(2 * BB * DD);               // dec L0 h ping-pong
  float* dh1p = alloc(BB * DD);                  // primed dec L1 h
  float* dc1g = alloc(BB * DD);                  // dec L1 c (global copy for qw)
  float* zeros = alloc(BB * DD);
  const size_t state_n = off;
  // ---- fully-overwritten buffers ----
  float* xs_emb = alloc((size_t)SS * BB * EE);
  float* gs_emb = alloc((size_t)TT * BB * EE);
  float* l0 = alloc((size_t)SS * BB * (2 * HH));
  float* enc_out = alloc((size_t)BB * SS * (2 * HH));
  float* encWe = alloc((size_t)BB * SS * DD);
  float* gxA = alloc(2ull * 2048ull * 2048ull);  // x-part gates, reused L0/L1
  float* h1_all = alloc((size_t)TT * BB * DD);
  float* qW = alloc(BB * DD);
  float* scores = alloc(BB * SS);
  float* wtd = alloc(BB * DD);
  (void)ws_size; (void)in_sizes; (void)n_in; (void)out_size;

  hipMemsetAsync(d_ws, 0, state_n * sizeof(float), stream);

  gather_k<<<dim3(SS, BB), 128, 0, stream>>>(x, in_emb, xs_emb, SS);
  gather_k<<<dim3(TT, BB), 128, 0, stream>>>(gs, out_emb, gs_emb, TT);

  // encoder layer 0: parallel x-part, then persistent recurrence
  gemv16_k<EE><<<dim3(512, 128, 2), 256, 0, stream>>>(
      xs_emb, EE, ewih0, EE, gxA, 2048, (size_t)4 * HH * EE, 2048ull * 2048ull);
  enc_mega3_k<<<NBLK, NTHR, 0, stream>>>(gxA, ewhh0, eb0, h0e, l0, BB * 2 * HH, 2 * HH, bar);
  // encoder layer 1
  gemv16_k<2 * HH><<<dim3(512, 128, 2), 256, 0, stream>>>(
      l0, 2 * HH, ewih1, 2 * HH, gxA, 2048, (size_t)4 * HH * 2 * HH, 2048ull * 2048ull);
  enc_mega3_k<<<NBLK, NTHR, 0, stream>>>(gxA, ewhh1, eb1, h1e, enc_out, 2 * HH, SS * 2 * HH,
                                         bar);
  // step-invariant attention term
  encwe_k<<<32768, 256, 0, stream>>>(enc_out, attn_w, encWe);

  // persistent decoder (prime + 128 steps)
  dec_mega3_k<<<NBLK, NTHR, 0, stream>>>(gs_emb, encWe, enc_out, attn_w, attn_b, attn_v,
                                         dwih0, dwhh0, db0, dwih1, dwhh1, db1, zeros, dh0,
                                         dh1p, dc1g, h1_all, qW, scores, wtd, bar + 2 * 2048);

  // all logits in one parallel launch
  logits_all_k<<<dim3(TT, VO / 4), 256, 0, stream>>>(h1_all, out_w, out_b, out);
}